// Round 3
// baseline (408.560 us; speedup 1.0000x reference)
//
#include <hip/hip_runtime.h>

// ROUND 3 = MEASUREMENT ROUND.
// Kernel body is byte-identical to round 1 (best, dur_us 272.5).
// kernel_launch fires it 3x back-to-back (idempotent writes) so that
//   kernel_duration = (dur_us - 272.5) / 2
// This disambiguates kernel~110us (keep optimizing) vs kernel~50us (roofline),
// which the top-5 counter table cannot resolve (all rows are the harness fill).

// Problem constants (fixed by the reference)
#define B_N   8
#define S_N   2048
#define K_N   21
#define L_N   16
#define CM_N  256
#define SCHUNK 128
#define CHUNKS (S_N / SCHUNK)   // 16
#define WSTRIDE 260              // floats: 1040 B row stride -> 16B-aligned rows, bank-spread

typedef float vfloat4 __attribute__((ext_vector_type(4)));

__global__ __launch_bounds__(256, 4) void pssm_proj_kernel(
    const float* __restrict__ x,     // [B,S,K]
    const float* __restrict__ W,     // [L,CM,K]
    const float* __restrict__ bias,  // [L,CM]
    float* __restrict__ out)         // [B,L,S,CM]
{
    __shared__ float xs[SCHUNK][24];
    __shared__ float wt[K_N][WSTRIDE];

    const int tid   = threadIdx.x;
    const int bx    = blockIdx.x;
    const int chunk = bx % CHUNKS;
    const int l     = (bx / CHUNKS) % L_N;
    const int b     = bx / (CHUNKS * L_N);
    const int s0    = chunk * SCHUNK;

    // ---- stage x[b, s0:s0+SCHUNK, 0:21] -> LDS (coalesced fp32 loads) ----
    const float* xbase = x + ((size_t)b * S_N + s0) * K_N;
    for (int idx = tid; idx < SCHUNK * K_N; idx += 256) {
        int r = idx / K_N;
        int k = idx - r * K_N;
        xs[r][k] = xbase[idx];
    }

    // ---- stage W[l] -> LDS transposed (coalesced reads, once per block) ----
    const float* wbase = W + (size_t)l * CM_N * K_N;   // 5376 floats
    for (int idx = tid; idx < CM_N * K_N; idx += 256) {
        int c = idx / K_N;
        int k = idx - c * K_N;
        wt[k][c] = wbase[idx];
    }

    __syncthreads();

    // ---- per-lane W fragment from LDS: 21 conflict-free ds_read_b128 ----
    const int lane = tid & 63;
    const int wave = tid >> 6;
    const int c0   = lane * 4;

    vfloat4 wfv[K_N];   // wfv[k] = { W[l][c0+0][k], ..., W[l][c0+3][k] }
#pragma unroll
    for (int k = 0; k < K_N; ++k)
        wfv[k] = *(const vfloat4*)(&wt[k][c0]);

    vfloat4 bv = *(const vfloat4*)(bias + l * CM_N + c0);  // 16B-aligned coalesced

    float* outbase = out + (((size_t)b * L_N + l) * S_N + s0) * CM_N + c0;

    // each wave sweeps rows {wave, wave+4, ...}: 32 rows/wave
    for (int i = 0; i < SCHUNK / 4; ++i) {
        const int r = i * 4 + wave;
        const vfloat4* xv = (const vfloat4*)(&xs[r][0]);  // wave-uniform broadcast reads

        float a0 = bv.x, a1 = bv.y, a2 = bv.z, a3 = bv.w;
#pragma unroll
        for (int kb = 0; kb < 6; ++kb) {
            vfloat4 xq = xv[kb];
            float xe[4] = {xq.x, xq.y, xq.z, xq.w};
#pragma unroll
            for (int e = 0; e < 4; ++e) {
                const int k = kb * 4 + e;
                if (k < K_N) {   // compile-time guard (K=21 < 24 pad; tail unused)
                    a0 += xe[e] * wfv[k].x;
                    a1 += xe[e] * wfv[k].y;
                    a2 += xe[e] * wfv[k].z;
                    a3 += xe[e] * wfv[k].w;
                }
            }
        }

        vfloat4 o = {a0, a1, a2, a3};
        *(vfloat4*)(outbase + (size_t)r * CM_N) = o;
    }
}

extern "C" void kernel_launch(void* const* d_in, const int* in_sizes, int n_in,
                              void* d_out, int out_size, void* d_ws, size_t ws_size,
                              hipStream_t stream) {
    const float* x    = (const float*)d_in[0];
    const float* W    = (const float*)d_in[1];
    const float* bias = (const float*)d_in[2];
    float* out        = (float*)d_out;

    dim3 grid(B_N * L_N * CHUNKS);   // 8*16*16 = 2048 blocks
    dim3 block(256);
    // 3 identical launches: writes are idempotent, so result is unchanged;
    // extra 2 launches expose the kernel's own duration as (dur_us - 272.5)/2.
    pssm_proj_kernel<<<grid, block, 0, stream>>>(x, W, bias, out);
    pssm_proj_kernel<<<grid, block, 0, stream>>>(x, W, bias, out);
    pssm_proj_kernel<<<grid, block, 0, stream>>>(x, W, bias, out);
}

// Round 4
// 285.042 us; speedup vs baseline: 1.4333x; 1.4333x over previous
//
#include <hip/hip_runtime.h>

// Round 4: amortize the x LDS-broadcast across layers.
// Round-3 measurement: kernel = 68us vs 43us write floor; per-CU LDS-pipe
// occupancy of the x row broadcast (~31us) is the dominant non-store cost.
// Fix: each block computes TWO layers for one (b, s-chunk) -> one x-row
// ds_read feeds 2x84 FMAs + 2 stores; per-CU LDS reads halve.

// Problem constants (fixed by the reference)
#define B_N   8
#define S_N   2048
#define K_N   21
#define L_N   16
#define CM_N  256
#define SCHUNK 128
#define CHUNKS (S_N / SCHUNK)   // 16
#define LPB    2                 // layers per block
#define LBLK   (L_N / LPB)       // 8 layer-pairs
#define WSTRIDE 260              // 1040B row stride: 16B-aligned, bank-spread

typedef float vfloat4 __attribute__((ext_vector_type(4)));

// 2 waves/EU (= 2 blocks/CU at 256 threads): caps VGPR at 256 so the
// 2x84-VGPR W fragment + 24-VGPR x row + accs (~210) doesn't spill.
// LDS: 12KB (xs) + 43.7KB (wt) = 55.9KB/block -> 2 blocks/CU = 112KB.
__global__ __launch_bounds__(256, 2) void pssm_proj_kernel(
    const float* __restrict__ x,     // [B,S,K]
    const float* __restrict__ W,     // [L,CM,K]
    const float* __restrict__ bias,  // [L,CM]
    float* __restrict__ out)         // [B,L,S,CM]
{
    __shared__ float xs[SCHUNK][24];
    __shared__ float wt[LPB][K_N][WSTRIDE];   // transposed: wt[ll][k][c]

    const int tid   = threadIdx.x;
    const int bx    = blockIdx.x;
    const int chunk = bx % CHUNKS;
    const int lp    = (bx / CHUNKS) % LBLK;
    const int b     = bx / (CHUNKS * LBLK);
    const int s0    = chunk * SCHUNK;
    const int l0    = lp * LPB;

    // ---- stage x[b, s0:s0+SCHUNK, 0:21] -> LDS (coalesced fp32 loads) ----
    const float* xbase = x + ((size_t)b * S_N + s0) * K_N;
    for (int idx = tid; idx < SCHUNK * K_N; idx += 256) {
        int r = idx / K_N;
        int k = idx - r * K_N;
        xs[r][k] = xbase[idx];
    }

    // ---- stage W[l0] and W[l0+1] -> LDS transposed (coalesced reads) ----
    const float* wbase = W + (size_t)l0 * CM_N * K_N;   // 2*5376 floats
    for (int idx = tid; idx < LPB * CM_N * K_N; idx += 256) {
        int ll  = idx / (CM_N * K_N);
        int rem = idx - ll * (CM_N * K_N);
        int c   = rem / K_N;
        int k   = rem - c * K_N;
        wt[ll][k][c] = wbase[idx];
    }

    __syncthreads();

    // ---- per-lane W fragments from LDS: 42 conflict-free ds_read_b128 ----
    const int lane = tid & 63;
    const int wave = tid >> 6;
    const int c0   = lane * 4;

    vfloat4 wfA[K_N], wfB[K_N];
#pragma unroll
    for (int k = 0; k < K_N; ++k) {
        wfA[k] = *(const vfloat4*)(&wt[0][k][c0]);
        wfB[k] = *(const vfloat4*)(&wt[1][k][c0]);
    }

    vfloat4 bvA = *(const vfloat4*)(bias + (l0 + 0) * CM_N + c0);
    vfloat4 bvB = *(const vfloat4*)(bias + (l0 + 1) * CM_N + c0);

    float* outA = out + (((size_t)b * L_N + l0) * S_N + s0) * CM_N + c0;
    float* outB = outA + (size_t)S_N * CM_N;   // next layer, contiguous

    // each wave sweeps rows {wave, wave+4, ...}: 32 rows/wave,
    // one x-row broadcast feeds BOTH layers (168 FMAs per 6 ds_reads).
    for (int i = 0; i < SCHUNK / 4; ++i) {
        const int r = i * 4 + wave;
        const vfloat4* xv = (const vfloat4*)(&xs[r][0]);  // wave-uniform broadcast

        float a0 = bvA.x, a1 = bvA.y, a2 = bvA.z, a3 = bvA.w;
        float d0 = bvB.x, d1 = bvB.y, d2 = bvB.z, d3 = bvB.w;
#pragma unroll
        for (int kb = 0; kb < 6; ++kb) {
            vfloat4 xq = xv[kb];
            float xe[4] = {xq.x, xq.y, xq.z, xq.w};
#pragma unroll
            for (int e = 0; e < 4; ++e) {
                const int k = kb * 4 + e;
                if (k < K_N) {   // compile-time guard (K=21 < 24 pad)
                    a0 += xe[e] * wfA[k].x;
                    a1 += xe[e] * wfA[k].y;
                    a2 += xe[e] * wfA[k].z;
                    a3 += xe[e] * wfA[k].w;
                    d0 += xe[e] * wfB[k].x;
                    d1 += xe[e] * wfB[k].y;
                    d2 += xe[e] * wfB[k].z;
                    d3 += xe[e] * wfB[k].w;
                }
            }
        }

        vfloat4 oA = {a0, a1, a2, a3};
        vfloat4 oB = {d0, d1, d2, d3};
        *(vfloat4*)(outA + (size_t)r * CM_N) = oA;
        *(vfloat4*)(outB + (size_t)r * CM_N) = oB;
    }
}

extern "C" void kernel_launch(void* const* d_in, const int* in_sizes, int n_in,
                              void* d_out, int out_size, void* d_ws, size_t ws_size,
                              hipStream_t stream) {
    const float* x    = (const float*)d_in[0];
    const float* W    = (const float*)d_in[1];
    const float* bias = (const float*)d_in[2];
    float* out        = (float*)d_out;

    dim3 grid(B_N * LBLK * CHUNKS);   // 8*8*16 = 1024 blocks
    dim3 block(256);
    pssm_proj_kernel<<<grid, block, 0, stream>>>(x, W, bias, out);
}

// Round 5
// 269.507 us; speedup vs baseline: 1.5160x; 1.0576x over previous
//
#include <hip/hip_runtime.h>

// Round 5: single resident dispatch round + time-multiplexed layers.
// Evidence: R3 measured kernel=68us vs 41us write floor. R4 showed halving LDS
// traffic at the cost of occupancy REGRESSES -> limiter is store-stream
// continuity. R1's 2048-block grid ran as 2 sequential rounds of 4 blocks/CU,
// paying the no-stores-issuing prologue bubble twice. This version: 1024
// blocks (exactly 4/CU, all resident at once), each doing 2 layer-passes off
// one x-stage; W[l1] is re-staged into LDS BEFORE hot-loop A so its latency
// hides under A's store stream. One W fragment live at a time -> VGPR ~110.

#define B_N   8
#define S_N   2048
#define K_N   21
#define L_N   16
#define CM_N  256
#define SCHUNK 128
#define CHUNKS (S_N / SCHUNK)   // 16
#define LGRP   2                 // layers per block, time-multiplexed
#define NLG    (L_N / LGRP)      // 8
#define WSTRIDE 260              // 1040B rows: 16B-aligned, bank-spread

typedef float vfloat4 __attribute__((ext_vector_type(4)));

__device__ __forceinline__ void stage_wt(float (*wt)[WSTRIDE],
                                         const float* __restrict__ W,
                                         int l, int tid) {
    // W[l] is 5376 floats, 16B-aligned (l*21504 bytes). Coalesced dwordx4
    // loads, scalar transposed ds_writes (one-time cost, ~2-3-way conflicts).
    const vfloat4* wb4 = (const vfloat4*)(W + (size_t)l * CM_N * K_N);
    for (int i4 = tid; i4 < CM_N * K_N / 4; i4 += 256) {
        vfloat4 v = wb4[i4];
        int e0 = i4 * 4;
#pragma unroll
        for (int j = 0; j < 4; ++j) {
            int e = e0 + j;
            int c = e / K_N, k = e - c * K_N;
            wt[k][c] = v[j];
        }
    }
}

__global__ __launch_bounds__(256, 4) void pssm_proj_kernel(
    const float* __restrict__ x,     // [B,S,K]
    const float* __restrict__ W,     // [L,CM,K]
    const float* __restrict__ bias,  // [L,CM]
    float* __restrict__ out)         // [B,L,S,CM]
{
    __shared__ float xs[SCHUNK][24];        // 12.3 KB
    __shared__ float wt[K_N][WSTRIDE];      // 21.8 KB -> 34.1 KB total, 4 blocks/CU

    const int tid   = threadIdx.x;
    const int bx    = blockIdx.x;
    const int chunk = bx % CHUNKS;
    const int lg    = (bx / CHUNKS) % NLG;
    const int b     = bx / (CHUNKS * NLG);
    const int s0    = chunk * SCHUNK;
    const int l0    = lg * LGRP;

    // ---- stage x[b, s0:s0+SCHUNK, :] -> LDS (dwordx4 loads, 672 instrs) ----
    const vfloat4* xb4 = (const vfloat4*)(x + ((size_t)b * S_N + s0) * K_N);
    for (int i4 = tid; i4 < SCHUNK * K_N / 4; i4 += 256) {
        vfloat4 v = xb4[i4];
        int e0 = i4 * 4;
#pragma unroll
        for (int j = 0; j < 4; ++j) {
            int e = e0 + j;
            int r = e / K_N, k = e - r * K_N;
            xs[r][k] = v[j];
        }
    }

    stage_wt(wt, W, l0, tid);      // layer A weights
    __syncthreads();

    const int lane = tid & 63;
    const int wave = tid >> 6;
    const int c0   = lane * 4;

    // ---- pass A fragment: 21 conflict-free ds_read_b128 ----
    vfloat4 wfv[K_N];
#pragma unroll
    for (int k = 0; k < K_N; ++k)
        wfv[k] = *(const vfloat4*)(&wt[k][c0]);

    __syncthreads();               // everyone has fragment A -> wt reusable

    // restage wt with layer B NOW: its global-load latency hides under
    // hot-loop A's ~10K-cycle FMA+store stream.
    stage_wt(wt, W, l0 + 1, tid);

    vfloat4 bv = *(const vfloat4*)(bias + (size_t)l0 * CM_N + c0);

    for (int pass = 0; pass < LGRP; ++pass) {
        const int l = l0 + pass;
        float* outbase = out + (((size_t)b * L_N + l) * S_N + s0) * CM_N + c0;

        // each wave sweeps rows {wave, wave+4, ...}: 32 rows/wave
        for (int i = 0; i < SCHUNK / 4; ++i) {
            const int r = i * 4 + wave;
            const vfloat4* xv = (const vfloat4*)(&xs[r][0]);  // broadcast reads

            float a0 = bv.x, a1 = bv.y, a2 = bv.z, a3 = bv.w;
#pragma unroll
            for (int kb = 0; kb < 6; ++kb) {
                vfloat4 xq = xv[kb];
                float xe[4] = {xq.x, xq.y, xq.z, xq.w};
#pragma unroll
                for (int e = 0; e < 4; ++e) {
                    const int k = kb * 4 + e;
                    if (k < K_N) {   // compile-time guard (K=21 < 24 pad)
                        a0 += xe[e] * wfv[k].x;
                        a1 += xe[e] * wfv[k].y;
                        a2 += xe[e] * wfv[k].z;
                        a3 += xe[e] * wfv[k].w;
                    }
                }
            }

            vfloat4 o = {a0, a1, a2, a3};
            *(vfloat4*)(outbase + (size_t)r * CM_N) = o;
        }

        if (pass == 0) {
            __syncthreads();       // wt[B] staged by all waves
            // swap in pass-B fragment + bias (A's regs dead -> reused)
#pragma unroll
            for (int k = 0; k < K_N; ++k)
                wfv[k] = *(const vfloat4*)(&wt[k][c0]);
            bv = *(const vfloat4*)(bias + (size_t)(l0 + 1) * CM_N + c0);
        }
    }
}

extern "C" void kernel_launch(void* const* d_in, const int* in_sizes, int n_in,
                              void* d_out, int out_size, void* d_ws, size_t ws_size,
                              hipStream_t stream) {
    const float* x    = (const float*)d_in[0];
    const float* W    = (const float*)d_in[1];
    const float* bias = (const float*)d_in[2];
    float* out        = (float*)d_out;

    dim3 grid(B_N * NLG * CHUNKS);   // 8*8*16 = 1024 blocks = exactly 4/CU
    dim3 block(256);
    pssm_proj_kernel<<<grid, block, 0, stream>>>(x, W, bias, out);
}